// Round 5
// baseline (633.329 us; speedup 1.0000x reference)
//
#include <hip/hip_runtime.h>
#include <stdint.h>

// B=32 S=512 E=512 H=8 Dh=64 R=3 L=2 ; M = B*S = 16384
// Inputs: float32 (+int32 indices) per the reference. Output: float32.
// Internal: bf16 workspace + bf16 MFMA, f32 accumulate.
// glo/ts score terms are per-(b,h,q) constants broadcast over k -> softmax-
// invariant -> Wg/bg/Wtq/btq/Wtk/btk/core are mathematically unused.

typedef short short8v __attribute__((ext_vector_type(8)));
typedef float f32x4 __attribute__((ext_vector_type(4)));

__device__ __forceinline__ float bf2f(unsigned short u) {
  union { unsigned int i; float f; } c;
  c.i = ((unsigned int)u) << 16;
  return c.f;
}
__device__ __forceinline__ unsigned short f2bf(float f) {
  union { float f; unsigned int i; } c;
  c.f = f;
  unsigned int u = c.i + 0x7FFFu + ((c.i >> 16) & 1u);  // RNE
  return (unsigned short)(u >> 16);
}

// ---------------- weight transpose (f32 in, bf16 out): out[c][r] = in[r][c] ----------------
__global__ __launch_bounds__(256) void transpose_k(const float* __restrict__ in,
                                                   unsigned short* __restrict__ out,
                                                   int R, int C) {
  __shared__ float t[32][33];
  int c0 = blockIdx.x * 32, r0 = blockIdx.y * 32;
  int lr = threadIdx.x >> 5, lc = threadIdx.x & 31;
#pragma unroll
  for (int i = 0; i < 4; ++i) {
    int r = lr + i * 8;
    t[r][lc] = in[(size_t)(r0 + r) * C + (c0 + lc)];
  }
  __syncthreads();
#pragma unroll
  for (int i = 0; i < 4; ++i) {
    int r = lr + i * 8;
    out[(size_t)(c0 + r) * R + (r0 + lc)] = f2bf(t[lc][r]);
  }
}

// ------- gather + label-select (f32 emb -> bf16): INP (16384x1024), QRY (16384x512) -------
__global__ __launch_bounds__(256) void build_inputs_k(
    const int* __restrict__ item_in, const int* __restrict__ skill_in,
    const int* __restrict__ label_in, const int* __restrict__ item_id,
    const int* __restrict__ skill_id, const float* __restrict__ iemb,
    const float* __restrict__ semb, unsigned short* __restrict__ INP,
    unsigned short* __restrict__ QRY) {
  int row = blockIdx.x;
  int t = threadIdx.x;
  int ii = item_in[row], si = skill_in[row], lb = label_in[row];
  int iq = item_id[row], sq = skill_id[row];
  int c = t * 4;         // [0,1024)
  int k = c & 511;       // position within the E=512 half
  const float* src = (k < 256) ? (iemb + (size_t)ii * 256 + k)
                               : (semb + (size_t)si * 256 + (k - 256));
  float4 v = *(const float4*)src;
  bool first = (c < 512);
  bool keep = (lb == 1) ? first : !first;  // inputs = [half*lab, half*(1-lab)]
  union { unsigned short u[4]; unsigned long long ll; } pk;
  pk.u[0] = keep ? f2bf(v.x) : 0;
  pk.u[1] = keep ? f2bf(v.y) : 0;
  pk.u[2] = keep ? f2bf(v.z) : 0;
  pk.u[3] = keep ? f2bf(v.w) : 0;
  *(unsigned long long*)(INP + (size_t)row * 1024 + c) = pk.ll;
  int qc = t * 2;  // [0,512)
  const float* qs = (qc < 256) ? (iemb + (size_t)iq * 256 + qc)
                               : (semb + (size_t)sq * 256 + (qc - 256));
  float2 q2 = *(const float2*)qs;
  union { unsigned short u[2]; unsigned int ui; } pq;
  pq.u[0] = f2bf(q2.x);
  pq.u[1] = f2bf(q2.y);
  *(unsigned int*)(QRY + (size_t)row * 512 + qc) = pq.ui;
}

// ---------------- GEMM: C[M,N] = epi(A[M,K] @ Bt[N,K]^T) ; 128x128 tile, BK=32 ----------------
__global__ __launch_bounds__(256, 2) void gemm_bt_k(
    const unsigned short* __restrict__ A, const unsigned short* __restrict__ Bt,
    unsigned short* __restrict__ C, int K, int ldc,
    const float* __restrict__ biasA, const float* __restrict__ biasB,
    int nsplit, float scale, int do_relu) {
  __shared__ __align__(16) unsigned short sA[128 * 32];
  __shared__ __align__(16) unsigned short sB[128 * 32];
  int nb = blockIdx.x, mb = blockIdx.y;
  int tid = threadIdx.x;
  int w = tid >> 6, lane = tid & 63, l16 = lane & 15, quad = lane >> 4;
  int wm = w & 1, wn = w >> 1;
  f32x4 acc[4][4];
#pragma unroll
  for (int i = 0; i < 4; ++i)
#pragma unroll
    for (int jn = 0; jn < 4; ++jn) acc[i][jn] = (f32x4){0.f, 0.f, 0.f, 0.f};

  for (int k0 = 0; k0 < K; k0 += 32) {
    int4 va[2], vb[2];
#pragma unroll
    for (int j = 0; j < 2; ++j) {
      int c = w * 128 + j * 64 + lane;  // 16B chunk id: row = c/4, kchunk = c%4
      int row = c >> 2, kc = c & 3;
      va[j] = *(const int4*)(A + (size_t)(mb * 128 + row) * K + k0 + kc * 8);
      vb[j] = *(const int4*)(Bt + (size_t)(nb * 128 + row) * K + k0 + kc * 8);
    }
    __syncthreads();  // previous iteration's LDS reads complete
#pragma unroll
    for (int j = 0; j < 2; ++j) {
      int c = w * 128 + j * 64 + lane;
      *(int4*)(sA + c * 8) = va[j];
      *(int4*)(sB + c * 8) = vb[j];
    }
    __syncthreads();
    short8v aF[4], bF[4];
#pragma unroll
    for (int mt = 0; mt < 4; ++mt)
      aF[mt] = *(const short8v*)(sA + (wm * 64 + mt * 16 + l16) * 32 + quad * 8);
#pragma unroll
    for (int nt = 0; nt < 4; ++nt)
      bF[nt] = *(const short8v*)(sB + (wn * 64 + nt * 16 + l16) * 32 + quad * 8);
#pragma unroll
    for (int mt = 0; mt < 4; ++mt)
#pragma unroll
      for (int nt = 0; nt < 4; ++nt)
        acc[mt][nt] =
            __builtin_amdgcn_mfma_f32_16x16x32_bf16(aF[mt], bF[nt], acc[mt][nt], 0, 0, 0);
  }
  // epilogue: +bias, *scale, optional relu, bf16 store. D: row=quad*4+r, col=l16
#pragma unroll
  for (int mt = 0; mt < 4; ++mt)
#pragma unroll
    for (int nt = 0; nt < 4; ++nt) {
      int col = nb * 128 + wn * 64 + nt * 16 + l16;
      float bs = (col < nsplit) ? biasA[col] : biasB[col - nsplit];
#pragma unroll
      for (int r = 0; r < 4; ++r) {
        int rowg = mb * 128 + wm * 64 + mt * 16 + quad * 4 + r;
        float v = (acc[mt][nt][r] + bs) * scale;
        if (do_relu) v = fmaxf(v, 0.f);
        C[(size_t)rowg * ldc + col] = f2bf(v);
      }
    }
}

// ---------------- V transpose + sigma permute into global ----------------
// VT[(b*8+h)*64 + d][sigma(kpos)] = V[b,kpos,h*64+d], sigma within 32-blocks:
// sigma(32T + 16t + 4qd + j) = 32T + 8qd + 4t + j
__global__ __launch_bounds__(256) void vperm_k(const unsigned short* __restrict__ KVb,
                                               unsigned short* __restrict__ VT) {
  int bh = blockIdx.x;
  int b = bh >> 3, h = bh & 7;
  int t = threadIdx.x;
  for (int it = 0; it < 128; ++it) {
    int idx = it * 256 + t;  // d-major: consecutive t -> consecutive kpos
    int d = idx >> 9, kp = idx & 511;
    unsigned short v = KVb[(size_t)(b * 512 + kp) * 1024 + 512 + h * 64 + d];
    int sg = (kp & ~31) | (((kp >> 2) & 3) << 3) | (((kp >> 4) & 1) << 2) | (kp & 3);
    VT[(size_t)(bh * 64 + d) * 512 + sg] = v;
  }
}

// ---------------- fused causal flash attention, LDS-free, one block per (b,h) ----------------
// Qb: [16384][512] bf16, pre-scaled by 1/sqrt(Dh). KVb: [16384][1024] = [K | V].
// VT: [2048][512] sigma-permuted V^T. Out: [16384][512] bf16.
// Scores computed TRANSPOSED (T = K*Q^T) so softmax'd P is already in MFMA
// A-operand layout; sigma-permuted V^T makes PV full-rate K=32 MFMAs.
// 4 waves/block; wave w handles q-tile-pairs {w, 7-w, 8+w, 15-w}:
// (w+1)+(8-w)+(9+w)+(16-w) = 34 k-blocks per wave, perfectly balanced.
__global__ __launch_bounds__(256) void attn_k(const unsigned short* __restrict__ Qb,
                                              const unsigned short* __restrict__ KVb,
                                              const unsigned short* __restrict__ VT,
                                              unsigned short* __restrict__ Out) {
  int bh = blockIdx.x;
  int b = bh >> 3, h = bh & 7;
  int tid = threadIdx.x;
  int w = tid >> 6, lane = tid & 63, l16 = lane & 15, quad = lane >> 4;
  const unsigned short* Kbase = KVb + (size_t)(b * 512) * 1024 + h * 64;  // row stride 1024
  const unsigned short* Vbase = VT + (size_t)(bh * 64) * 512;             // row stride 512
  f32x4 zf = {0.f, 0.f, 0.f, 0.f};

  int jl[4] = {w, 7 - w, 8 + w, 15 - w};  // w in [0,4): perfect 16-tile partition
  for (int ji = 0; ji < 4; ++ji) {
    int j = jl[ji];
    int q0 = j * 32;
    short8v qF[2][2];
#pragma unroll
    for (int u = 0; u < 2; ++u)
#pragma unroll
      for (int hf = 0; hf < 2; ++hf)
        qF[u][hf] = *(const short8v*)(Qb + (size_t)(b * 512 + q0 + u * 16 + l16) * 512 +
                                      h * 64 + hf * 32 + quad * 8);
    f32x4 O[2][4];
#pragma unroll
    for (int u = 0; u < 2; ++u)
#pragma unroll
      for (int dt = 0; dt < 4; ++dt) O[u][dt] = zf;
    float m_[2] = {-1e30f, -1e30f};
    float l_[2] = {0.f, 0.f};

    for (int kp = 0; kp <= j; ++kp) {
      int kb = kp * 32;
      short8v kF[2][2];
#pragma unroll
      for (int v = 0; v < 2; ++v)
#pragma unroll
        for (int hf = 0; hf < 2; ++hf)
          kF[v][hf] =
              *(const short8v*)(Kbase + (size_t)(kb + v * 16 + l16) * 1024 + hf * 32 + quad * 8);
      // T[kpos][q]: A=K rows, B=Q rows; D: row=kpos(16v+4quad+r), col=q(l16)
      f32x4 S[2][2];
#pragma unroll
      for (int u = 0; u < 2; ++u)
#pragma unroll
        for (int v = 0; v < 2; ++v) {
          f32x4 s0 = __builtin_amdgcn_mfma_f32_16x16x32_bf16(kF[v][0], qF[u][0], zf, 0, 0, 0);
          S[u][v] = __builtin_amdgcn_mfma_f32_16x16x32_bf16(kF[v][1], qF[u][1], s0, 0, 0, 0);
        }
      if (kp == j) {  // only diagonal pair needs causal masking
#pragma unroll
        for (int u = 0; u < 2; ++u)
#pragma unroll
          for (int v = 0; v < 2; ++v)
#pragma unroll
            for (int r = 0; r < 4; ++r)
              if (v * 16 + quad * 4 + r > u * 16 + l16) S[u][v][r] = -1e30f;
      }
      short8v pF[2];
#pragma unroll
      for (int u = 0; u < 2; ++u) {
        float tm = -1e30f;
#pragma unroll
        for (int v = 0; v < 2; ++v)
#pragma unroll
          for (int r = 0; r < 4; ++r) tm = fmaxf(tm, S[u][v][r]);
        tm = fmaxf(tm, __shfl_xor(tm, 16));
        tm = fmaxf(tm, __shfl_xor(tm, 32));
        float nm = fmaxf(m_[u], tm);
        float alpha = __expf(m_[u] - nm);
        float rs = 0.f;
        union { unsigned short u16[8]; short8v v8; } pk;
#pragma unroll
        for (int v = 0; v < 2; ++v)
#pragma unroll
          for (int r = 0; r < 4; ++r) {
            float e = __expf(S[u][v][r] - nm);
            rs += e;
            pk.u16[v * 4 + r] = f2bf(e);  // A-slot jj=4v+r <-> kpos kb+16v+4quad+r
          }
        rs += __shfl_xor(rs, 16);
        rs += __shfl_xor(rs, 32);
        l_[u] = l_[u] * alpha + rs;
        m_[u] = nm;
        float al[4];
#pragma unroll
        for (int r = 0; r < 4; ++r) al[r] = __shfl(alpha, quad * 4 + r);
#pragma unroll
        for (int dt = 0; dt < 4; ++dt)
#pragma unroll
          for (int r = 0; r < 4; ++r) O[u][dt][r] *= al[r];
        pF[u] = pk.v8;
      }
      short8v vF[4];  // B-slot (quad,jj) holds V[kb + 16(jj>>2)+4quad+(jj&3)][d] via sigma
#pragma unroll
      for (int dt = 0; dt < 4; ++dt)
        vF[dt] = *(const short8v*)(Vbase + (size_t)(dt * 16 + l16) * 512 + kb + quad * 8);
#pragma unroll
      for (int u = 0; u < 2; ++u)
#pragma unroll
        for (int dt = 0; dt < 4; ++dt)
          O[u][dt] = __builtin_amdgcn_mfma_f32_16x16x32_bf16(pF[u], vF[dt], O[u][dt], 0, 0, 0);
    }
    // normalize + store: O row(q) = q0+u*16+quad*4+r, col(d) = h*64+dt*16+l16
#pragma unroll
    for (int u = 0; u < 2; ++u) {
      float li = 1.f / l_[u];
      float lr[4];
#pragma unroll
      for (int r = 0; r < 4; ++r) lr[r] = __shfl(li, quad * 4 + r);
#pragma unroll
      for (int dt = 0; dt < 4; ++dt)
#pragma unroll
        for (int r = 0; r < 4; ++r)
          Out[(size_t)(b * 512 + q0 + u * 16 + quad * 4 + r) * 512 + h * 64 + dt * 16 + l16] =
              f2bf(O[u][dt][r] * lr[r]);
    }
  }
}

// -------- head: out[m] = (out0[m,:] + relu(res1[m,:])) . W_out + b_out  (f32 out) --------
__global__ __launch_bounds__(256) void final_k(const unsigned short* __restrict__ out0,
                                               const unsigned short* __restrict__ res1,
                                               const float* __restrict__ wout,
                                               const float* __restrict__ bout,
                                               float* __restrict__ dst) {
  int w = threadIdx.x >> 6, lane = threadIdx.x & 63;
  int row = blockIdx.x * 4 + w;
  const unsigned short* o = out0 + (size_t)row * 512 + lane * 8;
  const unsigned short* r = res1 + (size_t)row * 512 + lane * 8;
  const float* wv = wout + lane * 8;
  float acc = 0.f;
#pragma unroll
  for (int i = 0; i < 8; ++i) {
    float rv = bf2f(r[i]);
    acc += (bf2f(o[i]) + fmaxf(rv, 0.f)) * wv[i];
  }
#pragma unroll
  for (int off = 1; off <= 32; off <<= 1) acc += __shfl_xor(acc, off);
  if (lane == 0) dst[row] = acc + bout[0];
}

extern "C" void kernel_launch(void* const* d_in, const int* in_sizes, int n_in,
                              void* d_out, int out_size, void* d_ws, size_t ws_size,
                              hipStream_t stream) {
  (void)in_sizes; (void)n_in; (void)out_size; (void)ws_size;
  const int* item_inputs = (const int*)d_in[0];
  const int* skill_inputs = (const int*)d_in[1];
  const int* label_inputs = (const int*)d_in[2];
  const int* item_ids = (const int*)d_in[3];
  const int* skill_ids = (const int*)d_in[4];
  const float* item_emb = (const float*)d_in[5];
  const float* skill_emb = (const float*)d_in[6];
  const float* W_in = (const float*)d_in[7];
  const float* b_in = (const float*)d_in[8];
  const float* Wq = (const float*)d_in[9];
  const float* bq = (const float*)d_in[10];
  const float* Wk = (const float*)d_in[11];
  const float* bk = (const float*)d_in[12];
  const float* Wv = (const float*)d_in[13];
  const float* bv = (const float*)d_in[14];
  // d_in[15..21] (Wg,bg,Wtq,btq,Wtk,btk,core): softmax-invariant, unused
  const float* W_out = (const float*)d_in[22];
  const float* b_out = (const float*)d_in[23];

  // workspace layout (bf16 shorts), lifetime-overlapped; high-water ~116 MB
  unsigned short* ws = (unsigned short*)d_ws;
  unsigned short* INP = ws;                            // 16384*1024 (dead after GEMM0)
  unsigned short* OUT0 = ws;                           // overlays INP
  unsigned short* RES1 = ws + (size_t)16384 * 512;     // overlays INP upper half
  unsigned short* QRY = ws + (size_t)16384 * 1024;     // 16384*512
  unsigned short* X = QRY + (size_t)16384 * 512;       // 16384*512 (dead after KV GEMM 0)
  unsigned short* VT = X;                              // 2048*512, overlays X
  unsigned short* Qb = X + (size_t)16384 * 512;        // 16384*512
  unsigned short* KVb = Qb + (size_t)16384 * 512;      // 16384*1024
  unsigned short* WInT = KVb + (size_t)16384 * 1024;   // 1024*512
  unsigned short* WqT0 = WInT + 512 * 1024;            // 512*512
  unsigned short* WqT1 = WqT0 + 512 * 512;
  unsigned short* WkvT0 = WqT1 + 512 * 512;            // 1024*512
  unsigned short* WkvT1 = WkvT0 + 1024 * 512;

  // weight transposes into bf16 [N][K]
  transpose_k<<<dim3(16, 32), 256, 0, stream>>>(W_in, WInT, 1024, 512);
  transpose_k<<<dim3(16, 16), 256, 0, stream>>>(Wq, WqT0, 512, 512);
  transpose_k<<<dim3(16, 16), 256, 0, stream>>>(Wq + 262144, WqT1, 512, 512);
  transpose_k<<<dim3(16, 16), 256, 0, stream>>>(Wk, WkvT0, 512, 512);
  transpose_k<<<dim3(16, 16), 256, 0, stream>>>(Wv, WkvT0 + 262144, 512, 512);
  transpose_k<<<dim3(16, 16), 256, 0, stream>>>(Wk + 262144, WkvT1, 512, 512);
  transpose_k<<<dim3(16, 16), 256, 0, stream>>>(Wv + 262144, WkvT1 + 262144, 512, 512);

  build_inputs_k<<<16384, 256, 0, stream>>>(item_inputs, skill_inputs, label_inputs, item_ids,
                                            skill_ids, item_emb, skill_emb, INP, QRY);
  // x = relu(inputs @ W_in + b_in)   (INP dead afterwards)
  gemm_bt_k<<<dim3(4, 128), 256, 0, stream>>>(INP, WInT, X, 1024, 512, b_in, b_in, 1 << 30,
                                              1.0f, 1);

  const float SC = 0.125f;  // 1/sqrt(64), folded into Q projection
  // layer 0 (kv = x)
  gemm_bt_k<<<dim3(4, 128), 256, 0, stream>>>(QRY, WqT0, Qb, 512, 512, bq, bq, 1 << 30, SC, 0);
  gemm_bt_k<<<dim3(8, 128), 256, 0, stream>>>(X, WkvT0, KVb, 512, 1024, bk, bv, 512, 1.0f, 0);
  vperm_k<<<256, 256, 0, stream>>>(KVb, VT);  // X dead -> VT overlays it
  attn_k<<<256, 256, 0, stream>>>(Qb, KVb, VT, OUT0);
  // layer 1 (kv = out0)
  gemm_bt_k<<<dim3(4, 128), 256, 0, stream>>>(QRY, WqT1, Qb, 512, 512, bq + 512, bq + 512,
                                              1 << 30, SC, 0);
  gemm_bt_k<<<dim3(8, 128), 256, 0, stream>>>(OUT0, WkvT1, KVb, 512, 1024, bk + 512, bv + 512,
                                              512, 1.0f, 0);
  vperm_k<<<256, 256, 0, stream>>>(KVb, VT);
  attn_k<<<256, 256, 0, stream>>>(Qb, KVb, VT, RES1);
  // out = (out0 + relu(res1)) @ W_out + b_out   (f32 output)
  final_k<<<4096, 256, 0, stream>>>(OUT0, RES1, W_out, b_out, (float*)d_out);
}

// Round 6
// 611.479 us; speedup vs baseline: 1.0357x; 1.0357x over previous
//
#include <hip/hip_runtime.h>
#include <stdint.h>

// B=32 S=512 E=512 H=8 Dh=64 R=3 L=2 ; M = B*S = 16384
// Inputs: float32 (+int32 indices). Output: float32.
// Internal: bf16 workspace + bf16 MFMA, f32 accumulate.
// glo/ts score terms are per-(b,h,q) constants broadcast over k -> softmax-
// invariant -> Wg/bg/Wtq/btq/Wtk/btk/core are mathematically unused.

typedef short short8v __attribute__((ext_vector_type(8)));
typedef float f32x4 __attribute__((ext_vector_type(4)));

__device__ __forceinline__ float bf2f(unsigned short u) {
  union { unsigned int i; float f; } c;
  c.i = ((unsigned int)u) << 16;
  return c.f;
}
__device__ __forceinline__ unsigned short f2bf(float f) {
  union { float f; unsigned int i; } c;
  c.f = f;
  unsigned int u = c.i + 0x7FFFu + ((c.i >> 16) & 1u);  // RNE
  return (unsigned short)(u >> 16);
}

// ------------- batched weight transpose (f32 in -> bf16 [N][K] out), 1 dispatch -------------
struct WPtrs {
  const float* s[7];
  unsigned short* d[7];
};
__global__ __launch_bounds__(256) void transpose_all_k(WPtrs p) {
  __shared__ float t[32][33];
  int by = blockIdx.y;
  int mi, r0t;
  if (by < 32) { mi = 0; r0t = by; }            // W_in: 1024 rows
  else { mi = 1 + ((by - 32) >> 4); r0t = (by - 32) & 15; }  // 6x 512-row mats
  const float* in = p.s[mi];
  unsigned short* out = p.d[mi];
  int R = (mi == 0) ? 1024 : 512;  // source rows == out row-stride (K)
  const int C = 512;
  int c0 = blockIdx.x * 32, r0 = r0t * 32;
  int lr = threadIdx.x >> 5, lc = threadIdx.x & 31;
#pragma unroll
  for (int i = 0; i < 4; ++i) {
    int r = lr + i * 8;
    t[r][lc] = in[(size_t)(r0 + r) * C + (c0 + lc)];
  }
  __syncthreads();
#pragma unroll
  for (int i = 0; i < 4; ++i) {
    int r = lr + i * 8;
    out[(size_t)(c0 + r) * R + (r0 + lc)] = f2bf(t[lc][r]);
  }
}

// ------- gather + label-select (f32 emb -> bf16): INP (16384x1024), QRY (16384x512) -------
__global__ __launch_bounds__(256) void build_inputs_k(
    const int* __restrict__ item_in, const int* __restrict__ skill_in,
    const int* __restrict__ label_in, const int* __restrict__ item_id,
    const int* __restrict__ skill_id, const float* __restrict__ iemb,
    const float* __restrict__ semb, unsigned short* __restrict__ INP,
    unsigned short* __restrict__ QRY) {
  int row = blockIdx.x;
  int t = threadIdx.x;
  int ii = item_in[row], si = skill_in[row], lb = label_in[row];
  int iq = item_id[row], sq = skill_id[row];
  int c = t * 4;         // [0,1024)
  int k = c & 511;       // position within the E=512 half
  const float* src = (k < 256) ? (iemb + (size_t)ii * 256 + k)
                               : (semb + (size_t)si * 256 + (k - 256));
  float4 v = *(const float4*)src;
  bool first = (c < 512);
  bool keep = (lb == 1) ? first : !first;  // inputs = [half*lab, half*(1-lab)]
  union { unsigned short u[4]; unsigned long long ll; } pk;
  pk.u[0] = keep ? f2bf(v.x) : 0;
  pk.u[1] = keep ? f2bf(v.y) : 0;
  pk.u[2] = keep ? f2bf(v.z) : 0;
  pk.u[3] = keep ? f2bf(v.w) : 0;
  *(unsigned long long*)(INP + (size_t)row * 1024 + c) = pk.ll;
  int qc = t * 2;  // [0,512)
  const float* qs = (qc < 256) ? (iemb + (size_t)iq * 256 + qc)
                               : (semb + (size_t)sq * 256 + (qc - 256));
  float2 q2 = *(const float2*)qs;
  union { unsigned short u[2]; unsigned int ui; } pq;
  pq.u[0] = f2bf(q2.x);
  pq.u[1] = f2bf(q2.y);
  *(unsigned int*)(QRY + (size_t)row * 512 + qc) = pq.ui;
}

// ---------------- GEMM: C[M,N] = epi(A[M,K] @ Bt[N,K]^T) ; 128x128 tile, BK=32 ----------------
// mb = blockIdx.x (fast) so each A-tile is read by exactly one block-sequence;
// B (<=2 MB) broadcasts via L2/L3. Epilogue stages C-tile in LDS for full-line stores.
#define CT_LD 132  // 128 + 4 shorts pad: quad rows land on distinct bank groups
__global__ __launch_bounds__(256, 2) void gemm_bt_k(
    const unsigned short* __restrict__ A, const unsigned short* __restrict__ Bt,
    unsigned short* __restrict__ C, int K, int ldc,
    const float* __restrict__ biasA, const float* __restrict__ biasB,
    int nsplit, float scale, int do_relu) {
  __shared__ __align__(16) unsigned short uS[128 * CT_LD];  // 33792 B union
  unsigned short* sA = uS;             // 128*32 = 8 KB
  unsigned short* sB = uS + 128 * 32;  // 8 KB
  unsigned short* Ct = uS;             // full 128x132 after k-loop
  int mb = blockIdx.x, nb = blockIdx.y;
  int tid = threadIdx.x;
  int w = tid >> 6, lane = tid & 63, l16 = lane & 15, quad = lane >> 4;
  int wm = w & 1, wn = w >> 1;
  f32x4 acc[4][4];
#pragma unroll
  for (int i = 0; i < 4; ++i)
#pragma unroll
    for (int jn = 0; jn < 4; ++jn) acc[i][jn] = (f32x4){0.f, 0.f, 0.f, 0.f};

  for (int k0 = 0; k0 < K; k0 += 32) {
    int4 va[2], vb[2];
#pragma unroll
    for (int j = 0; j < 2; ++j) {
      int c = w * 128 + j * 64 + lane;  // 16B chunk id: row = c/4, kchunk = c%4
      int row = c >> 2, kc = c & 3;
      va[j] = *(const int4*)(A + (size_t)(mb * 128 + row) * K + k0 + kc * 8);
      vb[j] = *(const int4*)(Bt + (size_t)(nb * 128 + row) * K + k0 + kc * 8);
    }
    __syncthreads();  // previous iteration's LDS reads complete
#pragma unroll
    for (int j = 0; j < 2; ++j) {
      int c = w * 128 + j * 64 + lane;
      *(int4*)(sA + c * 8) = va[j];
      *(int4*)(sB + c * 8) = vb[j];
    }
    __syncthreads();
    short8v aF[4], bF[4];
#pragma unroll
    for (int mt = 0; mt < 4; ++mt)
      aF[mt] = *(const short8v*)(sA + (wm * 64 + mt * 16 + l16) * 32 + quad * 8);
#pragma unroll
    for (int nt = 0; nt < 4; ++nt)
      bF[nt] = *(const short8v*)(sB + (wn * 64 + nt * 16 + l16) * 32 + quad * 8);
#pragma unroll
    for (int mt = 0; mt < 4; ++mt)
#pragma unroll
      for (int nt = 0; nt < 4; ++nt)
        acc[mt][nt] =
            __builtin_amdgcn_mfma_f32_16x16x32_bf16(aF[mt], bF[nt], acc[mt][nt], 0, 0, 0);
  }
  // epilogue: +bias, *scale, optional relu -> bf16 C-tile in LDS -> coalesced store
  __syncthreads();  // all sA/sB reads done before aliasing as Ct
#pragma unroll
  for (int mt = 0; mt < 4; ++mt)
#pragma unroll
    for (int nt = 0; nt < 4; ++nt) {
      int col = wn * 64 + nt * 16 + l16;
      int gcol = nb * 128 + col;
      float bs = (gcol < nsplit) ? biasA[gcol] : biasB[gcol - nsplit];
#pragma unroll
      for (int r = 0; r < 4; ++r) {
        int row = wm * 64 + mt * 16 + quad * 4 + r;
        float v = (acc[mt][nt][r] + bs) * scale;
        if (do_relu) v = fmaxf(v, 0.f);
        Ct[row * CT_LD + col] = f2bf(v);
      }
    }
  __syncthreads();
#pragma unroll
  for (int it = 0; it < 8; ++it) {
    int row = it * 16 + (tid >> 4);  // 16 rows per iteration
    int col8 = (tid & 15) * 8;       // 16B per lane, 256B contiguous per row
    *(int4*)(C + (size_t)(mb * 128 + row) * ldc + nb * 128 + col8) =
        *(const int4*)(Ct + row * CT_LD + col8);
  }
}

// ---------------- V transpose + sigma permute into global ----------------
// VT[(b*8+h)*64 + d][sigma(kpos)] = V[b,kpos,h*64+d], sigma within 32-blocks:
// sigma(32T + 16t + 4qd + j) = 32T + 8qd + 4t + j
__global__ __launch_bounds__(256) void vperm_k(const unsigned short* __restrict__ KVb,
                                               unsigned short* __restrict__ VT) {
  int bh = blockIdx.x;
  int b = bh >> 3, h = bh & 7;
  int t = threadIdx.x;
  for (int it = 0; it < 128; ++it) {
    int idx = it * 256 + t;  // d-major: consecutive t -> consecutive kpos
    int d = idx >> 9, kp = idx & 511;
    unsigned short v = KVb[(size_t)(b * 512 + kp) * 1024 + 512 + h * 64 + d];
    int sg = (kp & ~31) | (((kp >> 2) & 3) << 3) | (((kp >> 4) & 1) << 2) | (kp & 3);
    VT[(size_t)(bh * 64 + d) * 512 + sg] = v;
  }
}

// ---------------- fused causal flash attention, LDS-free, one block per (b,h) ----------------
// Qb: [16384][512] bf16, pre-scaled by 1/sqrt(Dh). KVb: [16384][1024] = [K | V].
// VT: [2048][512] sigma-permuted V^T. Out: [16384][512] bf16.
// Scores computed TRANSPOSED (T = K*Q^T) so softmax'd P is already in MFMA
// A-operand layout; sigma-permuted V^T makes PV full-rate K=32 MFMAs.
// 4 waves/block; wave w handles q-tile-pairs {w, 7-w, 8+w, 15-w}:
// (w+1)+(8-w)+(9+w)+(16-w) = 34 k-blocks per wave, perfectly balanced.
__global__ __launch_bounds__(256) void attn_k(const unsigned short* __restrict__ Qb,
                                              const unsigned short* __restrict__ KVb,
                                              const unsigned short* __restrict__ VT,
                                              unsigned short* __restrict__ Out) {
  int bh = blockIdx.x;
  int b = bh >> 3, h = bh & 7;
  int tid = threadIdx.x;
  int w = tid >> 6, lane = tid & 63, l16 = lane & 15, quad = lane >> 4;
  const unsigned short* Kbase = KVb + (size_t)(b * 512) * 1024 + h * 64;  // row stride 1024
  const unsigned short* Vbase = VT + (size_t)(bh * 64) * 512;             // row stride 512
  f32x4 zf = {0.f, 0.f, 0.f, 0.f};

  int jl[4] = {w, 7 - w, 8 + w, 15 - w};  // w in [0,4): perfect 16-tile partition
  for (int ji = 0; ji < 4; ++ji) {
    int j = jl[ji];
    int q0 = j * 32;
    short8v qF[2][2];
#pragma unroll
    for (int u = 0; u < 2; ++u)
#pragma unroll
      for (int hf = 0; hf < 2; ++hf)
        qF[u][hf] = *(const short8v*)(Qb + (size_t)(b * 512 + q0 + u * 16 + l16) * 512 +
                                      h * 64 + hf * 32 + quad * 8);
    f32x4 O[2][4];
#pragma unroll
    for (int u = 0; u < 2; ++u)
#pragma unroll
      for (int dt = 0; dt < 4; ++dt) O[u][dt] = zf;
    float m_[2] = {-1e30f, -1e30f};
    float l_[2] = {0.f, 0.f};

    for (int kp = 0; kp <= j; ++kp) {
      int kb = kp * 32;
      short8v kF[2][2];
#pragma unroll
      for (int v = 0; v < 2; ++v)
#pragma unroll
        for (int hf = 0; hf < 2; ++hf)
          kF[v][hf] =
              *(const short8v*)(Kbase + (size_t)(kb + v * 16 + l16) * 1024 + hf * 32 + quad * 8);
      // T[kpos][q]: A=K rows, B=Q rows; D: row=kpos(16v+4quad+r), col=q(l16)
      f32x4 S[2][2];
#pragma unroll
      for (int u = 0; u < 2; ++u)
#pragma unroll
        for (int v = 0; v < 2; ++v) {
          f32x4 s0 = __builtin_amdgcn_mfma_f32_16x16x32_bf16(kF[v][0], qF[u][0], zf, 0, 0, 0);
          S[u][v] = __builtin_amdgcn_mfma_f32_16x16x32_bf16(kF[v][1], qF[u][1], s0, 0, 0, 0);
        }
      if (kp == j) {  // only diagonal pair needs causal masking
#pragma unroll
        for (int u = 0; u < 2; ++u)
#pragma unroll
          for (int v = 0; v < 2; ++v)
#pragma unroll
            for (int r = 0; r < 4; ++r)
              if (v * 16 + quad * 4 + r > u * 16 + l16) S[u][v][r] = -1e30f;
      }
      short8v pF[2];
#pragma unroll
      for (int u = 0; u < 2; ++u) {
        float tm = -1e30f;
#pragma unroll
        for (int v = 0; v < 2; ++v)
#pragma unroll
          for (int r = 0; r < 4; ++r) tm = fmaxf(tm, S[u][v][r]);
        tm = fmaxf(tm, __shfl_xor(tm, 16));
        tm = fmaxf(tm, __shfl_xor(tm, 32));
        float nm = fmaxf(m_[u], tm);
        float alpha = __expf(m_[u] - nm);
        float rs = 0.f;
        union { unsigned short u16[8]; short8v v8; } pk;
#pragma unroll
        for (int v = 0; v < 2; ++v)
#pragma unroll
          for (int r = 0; r < 4; ++r) {
            float e = __expf(S[u][v][r] - nm);
            rs += e;
            pk.u16[v * 4 + r] = f2bf(e);  // A-slot jj=4v+r <-> kpos kb+16v+4quad+r
          }
        rs += __shfl_xor(rs, 16);
        rs += __shfl_xor(rs, 32);
        l_[u] = l_[u] * alpha + rs;
        m_[u] = nm;
        float al[4];
#pragma unroll
        for (int r = 0; r < 4; ++r) al[r] = __shfl(alpha, quad * 4 + r);
#pragma unroll
        for (int dt = 0; dt < 4; ++dt)
#pragma unroll
          for (int r = 0; r < 4; ++r) O[u][dt][r] *= al[r];
        pF[u] = pk.v8;
      }
      short8v vF[4];  // B-slot (quad,jj) holds V[kb + 16(jj>>2)+4quad+(jj&3)][d] via sigma
#pragma unroll
      for (int dt = 0; dt < 4; ++dt)
        vF[dt] = *(const short8v*)(Vbase + (size_t)(dt * 16 + l16) * 512 + kb + quad * 8);
#pragma unroll
      for (int u = 0; u < 2; ++u)
#pragma unroll
        for (int dt = 0; dt < 4; ++dt)
          O[u][dt] = __builtin_amdgcn_mfma_f32_16x16x32_bf16(pF[u], vF[dt], O[u][dt], 0, 0, 0);
    }
    // normalize + store: O row(q) = q0+u*16+quad*4+r, col(d) = h*64+dt*16+l16
#pragma unroll
    for (int u = 0; u < 2; ++u) {
      float li = 1.f / l_[u];
      float lr[4];
#pragma unroll
      for (int r = 0; r < 4; ++r) lr[r] = __shfl(li, quad * 4 + r);
#pragma unroll
      for (int dt = 0; dt < 4; ++dt)
#pragma unroll
        for (int r = 0; r < 4; ++r)
          Out[(size_t)(b * 512 + q0 + u * 16 + quad * 4 + r) * 512 + h * 64 + dt * 16 + l16] =
              f2bf(O[u][dt][r] * lr[r]);
    }
  }
}

// -------- head: out[m] = (out0[m,:] + relu(res1[m,:])) . W_out + b_out  (f32 out) --------
__global__ __launch_bounds__(256) void final_k(const unsigned short* __restrict__ out0,
                                               const unsigned short* __restrict__ res1,
                                               const float* __restrict__ wout,
                                               const float* __restrict__ bout,
                                               float* __restrict__ dst) {
  int w = threadIdx.x >> 6, lane = threadIdx.x & 63;
  int row = blockIdx.x * 4 + w;
  const unsigned short* o = out0 + (size_t)row * 512 + lane * 8;
  const unsigned short* r = res1 + (size_t)row * 512 + lane * 8;
  const float* wv = wout + lane * 8;
  float acc = 0.f;
#pragma unroll
  for (int i = 0; i < 8; ++i) {
    float rv = bf2f(r[i]);
    acc += (bf2f(o[i]) + fmaxf(rv, 0.f)) * wv[i];
  }
#pragma unroll
  for (int off = 1; off <= 32; off <<= 1) acc += __shfl_xor(acc, off);
  if (lane == 0) dst[row] = acc + bout[0];
}

extern "C" void kernel_launch(void* const* d_in, const int* in_sizes, int n_in,
                              void* d_out, int out_size, void* d_ws, size_t ws_size,
                              hipStream_t stream) {
  (void)in_sizes; (void)n_in; (void)out_size; (void)ws_size;
  const int* item_inputs = (const int*)d_in[0];
  const int* skill_inputs = (const int*)d_in[1];
  const int* label_inputs = (const int*)d_in[2];
  const int* item_ids = (const int*)d_in[3];
  const int* skill_ids = (const int*)d_in[4];
  const float* item_emb = (const float*)d_in[5];
  const float* skill_emb = (const float*)d_in[6];
  const float* W_in = (const float*)d_in[7];
  const float* b_in = (const float*)d_in[8];
  const float* Wq = (const float*)d_in[9];
  const float* bq = (const float*)d_in[10];
  const float* Wk = (const float*)d_in[11];
  const float* bk = (const float*)d_in[12];
  const float* Wv = (const float*)d_in[13];
  const float* bv = (const float*)d_in[14];
  // d_in[15..21] (Wg,bg,Wtq,btq,Wtk,btk,core): softmax-invariant, unused
  const float* W_out = (const float*)d_in[22];
  const float* b_out = (const float*)d_in[23];

  // workspace layout (bf16 shorts), lifetime-overlapped; high-water ~116 MB
  unsigned short* ws = (unsigned short*)d_ws;
  unsigned short* INP = ws;                            // 16384*1024 (dead after GEMM0)
  unsigned short* OUT0 = ws;                           // overlays INP
  unsigned short* RES1 = ws + (size_t)16384 * 512;     // overlays INP upper half
  unsigned short* QRY = ws + (size_t)16384 * 1024;     // 16384*512
  unsigned short* X = QRY + (size_t)16384 * 512;       // 16384*512 (dead after KV GEMM 0)
  unsigned short* VT = X;                              // 2048*512, overlays X
  unsigned short* Qb = X + (size_t)16384 * 512;        // 16384*512
  unsigned short* KVb = Qb + (size_t)16384 * 512;      // 16384*1024
  unsigned short* WInT = KVb + (size_t)16384 * 1024;   // 1024*512
  unsigned short* WqT0 = WInT + 512 * 1024;            // 512*512
  unsigned short* WqT1 = WqT0 + 512 * 512;
  unsigned short* WkvT0 = WqT1 + 512 * 512;            // 1024*512
  unsigned short* WkvT1 = WkvT0 + 1024 * 512;

  // all 7 weight transposes in one dispatch
  WPtrs p;
  p.s[0] = W_in;           p.d[0] = WInT;
  p.s[1] = Wq;             p.d[1] = WqT0;
  p.s[2] = Wq + 262144;    p.d[2] = WqT1;
  p.s[3] = Wk;             p.d[3] = WkvT0;
  p.s[4] = Wv;             p.d[4] = WkvT0 + 262144;
  p.s[5] = Wk + 262144;    p.d[5] = WkvT1;
  p.s[6] = Wv + 262144;    p.d[6] = WkvT1 + 262144;
  transpose_all_k<<<dim3(16, 128), 256, 0, stream>>>(p);

  build_inputs_k<<<16384, 256, 0, stream>>>(item_inputs, skill_inputs, label_inputs, item_ids,
                                            skill_ids, item_emb, skill_emb, INP, QRY);
  // x = relu(inputs @ W_in + b_in)   (INP dead afterwards)
  gemm_bt_k<<<dim3(128, 4), 256, 0, stream>>>(INP, WInT, X, 1024, 512, b_in, b_in, 1 << 30,
                                              1.0f, 1);

  const float SC = 0.125f;  // 1/sqrt(64), folded into Q projection
  // layer 0 (kv = x)
  gemm_bt_k<<<dim3(128, 4), 256, 0, stream>>>(QRY, WqT0, Qb, 512, 512, bq, bq, 1 << 30, SC, 0);
  gemm_bt_k<<<dim3(128, 8), 256, 0, stream>>>(X, WkvT0, KVb, 512, 1024, bk, bv, 512, 1.0f, 0);
  vperm_k<<<256, 256, 0, stream>>>(KVb, VT);  // X dead -> VT overlays it
  attn_k<<<256, 256, 0, stream>>>(Qb, KVb, VT, OUT0);
  // layer 1 (kv = out0)
  gemm_bt_k<<<dim3(128, 4), 256, 0, stream>>>(QRY, WqT1, Qb, 512, 512, bq + 512, bq + 512,
                                              1 << 30, SC, 0);
  gemm_bt_k<<<dim3(128, 8), 256, 0, stream>>>(OUT0, WkvT1, KVb, 512, 1024, bk + 512, bv + 512,
                                              512, 1.0f, 0);
  vperm_k<<<256, 256, 0, stream>>>(KVb, VT);
  attn_k<<<256, 256, 0, stream>>>(Qb, KVb, VT, RES1);
  // out = (out0 + relu(res1)) @ W_out + b_out   (f32 output)
  final_k<<<4096, 256, 0, stream>>>(OUT0, RES1, W_out, b_out, (float*)d_out);
}

// Round 7
// 399.835 us; speedup vs baseline: 1.5840x; 1.5293x over previous
//
#include <hip/hip_runtime.h>
#include <stdint.h>

// B=32 S=512 E=512 H=8 Dh=64 R=3 L=2 ; M = B*S = 16384
// Inputs: float32 (+int32 indices). Output: float32.
// Internal: bf16 workspace + bf16 MFMA, f32 accumulate.
// glo/ts score terms are per-(b,h,q) constants broadcast over k -> softmax-
// invariant -> Wg/bg/Wtq/btq/Wtk/btk/core are mathematically unused.

typedef short short8v __attribute__((ext_vector_type(8)));
typedef float f32x4 __attribute__((ext_vector_type(4)));

__device__ __forceinline__ float bf2f(unsigned short u) {
  union { unsigned int i; float f; } c;
  c.i = ((unsigned int)u) << 16;
  return c.f;
}
__device__ __forceinline__ unsigned short f2bf(float f) {
  union { float f; unsigned int i; } c;
  c.f = f;
  unsigned int u = c.i + 0x7FFFu + ((c.i >> 16) & 1u);  // RNE
  return (unsigned short)(u >> 16);
}

// async global->LDS, 16B per lane; LDS dest must be wave-uniform base + lane*16
__device__ __forceinline__ void g2l16(const void* g, void* l) {
  __builtin_amdgcn_global_load_lds(
      (const __attribute__((address_space(1))) unsigned int*)g,
      (__attribute__((address_space(3))) unsigned int*)l, 16, 0, 0);
}

// ------------- batched weight transpose (f32 in -> bf16 [N][K] out), 1 dispatch -------------
struct WPtrs {
  const float* s[7];
  unsigned short* d[7];
};
__global__ __launch_bounds__(256) void transpose_all_k(WPtrs p) {
  __shared__ float t[32][33];
  int by = blockIdx.y;
  int mi, r0t;
  if (by < 32) { mi = 0; r0t = by; }            // W_in: 1024 rows
  else { mi = 1 + ((by - 32) >> 4); r0t = (by - 32) & 15; }  // 6x 512-row mats
  const float* in = p.s[mi];
  unsigned short* out = p.d[mi];
  int R = (mi == 0) ? 1024 : 512;  // source rows == out row-stride (K)
  const int C = 512;
  int c0 = blockIdx.x * 32, r0 = r0t * 32;
  int lr = threadIdx.x >> 5, lc = threadIdx.x & 31;
#pragma unroll
  for (int i = 0; i < 4; ++i) {
    int r = lr + i * 8;
    t[r][lc] = in[(size_t)(r0 + r) * C + (c0 + lc)];
  }
  __syncthreads();
#pragma unroll
  for (int i = 0; i < 4; ++i) {
    int r = lr + i * 8;
    out[(size_t)(c0 + r) * R + (r0 + lc)] = f2bf(t[lc][r]);
  }
}

// ------- gather + label-select (f32 emb -> bf16): INP (16384x1024), QRY (16384x512) -------
// one row per wave, 4 rows per block
__global__ __launch_bounds__(256) void build_inputs_k(
    const int* __restrict__ item_in, const int* __restrict__ skill_in,
    const int* __restrict__ label_in, const int* __restrict__ item_id,
    const int* __restrict__ skill_id, const float* __restrict__ iemb,
    const float* __restrict__ semb, unsigned short* __restrict__ INP,
    unsigned short* __restrict__ QRY) {
  int w = threadIdx.x >> 6, lane = threadIdx.x & 63;
  int row = blockIdx.x * 4 + w;
  int ii = item_in[row], si = skill_in[row], lb = label_in[row];
  int iq = item_id[row], sq = skill_id[row];
  // INP: lane covers shorts [lane*16, lane*16+16)  (chunk stays within one 256-half)
  int c = lane * 16;
  int k = c & 511;
  const float* src = (k < 256) ? (iemb + (size_t)ii * 256 + k)
                               : (semb + (size_t)si * 256 + (k - 256));
  bool keep = ((lb == 1) == (c < 512));
  union { unsigned short u[16]; int4 v[2]; } o;
#pragma unroll
  for (int i = 0; i < 16; ++i) o.u[i] = keep ? f2bf(src[i]) : 0;
  *(int4*)(INP + (size_t)row * 1024 + c) = o.v[0];
  *(int4*)(INP + (size_t)row * 1024 + c + 8) = o.v[1];
  // QRY: lane covers shorts [lane*8, lane*8+8)
  int qc = lane * 8;
  const float* qs = (qc < 256) ? (iemb + (size_t)iq * 256 + qc)
                               : (semb + (size_t)sq * 256 + (qc - 256));
  union { unsigned short u[8]; int4 v; } q;
#pragma unroll
  for (int i = 0; i < 8; ++i) q.u[i] = f2bf(qs[i]);
  *(int4*)(QRY + (size_t)row * 512 + qc) = q.v;
}

// ---------------- GEMM: C[M,N] = epi(A[M,K] @ Bt[N,K]^T) ; 128x128 tile, BK=32 ----------------
// mb = blockIdx.x (fast): each XCD keeps the same A-slice L2-resident across nb.
// global_load_lds width-16 async staging (m97 structure); LDS-staged coalesced epilogue.
#define CT_LD 132  // 128 + 4 shorts pad
__global__ __launch_bounds__(256, 4) void gemm_bt_k(
    const unsigned short* __restrict__ A, const unsigned short* __restrict__ Bt,
    unsigned short* __restrict__ C, int K, int ldc,
    const float* __restrict__ biasA, const float* __restrict__ biasB,
    int nsplit, float scale, int do_relu) {
  __shared__ __align__(16) unsigned short uS[128 * CT_LD];  // 33792 B union
  unsigned short* sA = uS;             // 128*32 = 8 KB
  unsigned short* sB = uS + 128 * 32;  // 8 KB
  unsigned short* Ct = uS;             // full 128x132 in epilogue
  int mb = blockIdx.x, nb = blockIdx.y;
  int tid = threadIdx.x;
  int w = tid >> 6, lane = tid & 63, l16 = lane & 15, quad = lane >> 4;
  int wm = w & 1, wn = w >> 1;
  f32x4 acc[4][4];
#pragma unroll
  for (int i = 0; i < 4; ++i)
#pragma unroll
    for (int jn = 0; jn < 4; ++jn) acc[i][jn] = (f32x4){0.f, 0.f, 0.f, 0.f};

  for (int k0 = 0; k0 < K; k0 += 32) {
    __syncthreads();  // previous iteration's ds_reads complete before overwrite
#pragma unroll
    for (int j = 0; j < 2; ++j) {
      int c = w * 128 + j * 64 + lane;  // 16B chunk id: row = c/4, kchunk = c%4
      int row = c >> 2, kc = c & 3;
      g2l16(A + (size_t)(mb * 128 + row) * K + k0 + kc * 8, sA + (size_t)c * 8);
      g2l16(Bt + (size_t)(nb * 128 + row) * K + k0 + kc * 8, sB + (size_t)c * 8);
    }
    __syncthreads();  // barrier drains vmcnt(0) -> LDS ready
    short8v aF[4], bF[4];
#pragma unroll
    for (int mt = 0; mt < 4; ++mt)
      aF[mt] = *(const short8v*)(sA + (wm * 64 + mt * 16 + l16) * 32 + quad * 8);
#pragma unroll
    for (int nt = 0; nt < 4; ++nt)
      bF[nt] = *(const short8v*)(sB + (wn * 64 + nt * 16 + l16) * 32 + quad * 8);
#pragma unroll
    for (int mt = 0; mt < 4; ++mt)
#pragma unroll
      for (int nt = 0; nt < 4; ++nt)
        acc[mt][nt] =
            __builtin_amdgcn_mfma_f32_16x16x32_bf16(aF[mt], bF[nt], acc[mt][nt], 0, 0, 0);
  }
  // epilogue: +bias, *scale, optional relu -> bf16 C-tile in LDS -> coalesced store
  __syncthreads();  // all sA/sB reads done before aliasing as Ct
#pragma unroll
  for (int mt = 0; mt < 4; ++mt)
#pragma unroll
    for (int nt = 0; nt < 4; ++nt) {
      int col = wn * 64 + nt * 16 + l16;
      int gcol = nb * 128 + col;
      float bs = (gcol < nsplit) ? biasA[gcol] : biasB[gcol - nsplit];
#pragma unroll
      for (int r = 0; r < 4; ++r) {
        int row = wm * 64 + mt * 16 + quad * 4 + r;
        float v = (acc[mt][nt][r] + bs) * scale;
        if (do_relu) v = fmaxf(v, 0.f);
        Ct[row * CT_LD + col] = f2bf(v);
      }
    }
  __syncthreads();
#pragma unroll
  for (int it = 0; it < 8; ++it) {
    int row = it * 16 + (tid >> 4);  // 16 rows per iteration
    int col8 = (tid & 15) * 8;       // 16B per lane, 256B contiguous per row
    *(int4*)(C + (size_t)(mb * 128 + row) * ldc + nb * 128 + col8) =
        *(const int4*)(Ct + row * CT_LD + col8);
  }
}

// ---------------- V transpose + sigma permute into global ----------------
// VT[(b*8+h)*64 + d][sigma(kpos)] = V[b,kpos,h*64+d], sigma within 32-blocks:
// sigma(32T + 16t + 4qd + j) = 32T + 8qd + 4t + j
__global__ __launch_bounds__(256) void vperm_k(const unsigned short* __restrict__ KVb,
                                               unsigned short* __restrict__ VT) {
  int bh = blockIdx.x;
  int b = bh >> 3, h = bh & 7;
  int t = threadIdx.x;
  for (int it = 0; it < 128; ++it) {
    int idx = it * 256 + t;  // d-major: consecutive t -> consecutive kpos
    int d = idx >> 9, kp = idx & 511;
    unsigned short v = KVb[(size_t)(b * 512 + kp) * 1024 + 512 + h * 64 + d];
    int sg = (kp & ~31) | (((kp >> 2) & 3) << 3) | (((kp >> 4) & 1) << 2) | (kp & 3);
    VT[(size_t)(bh * 64 + d) * 512 + sg] = v;
  }
}

// ---------------- fused causal flash attention, LDS-free, one block per (b,h) ----------------
// Qb: [16384][512] bf16, pre-scaled by 1/sqrt(Dh). KVb: [16384][1024] = [K | V].
// VT: [2048][512] sigma-permuted V^T. Out: [16384][512] bf16.
// Scores computed TRANSPOSED (T = K*Q^T) so softmax'd P is already in MFMA
// A-operand layout; sigma-permuted V^T makes PV full-rate K=32 MFMAs.
// 4 waves/block; wave w handles q-tile-pairs {w, 7-w, 8+w, 15-w}: 34 k-blocks each.
__global__ __launch_bounds__(256) void attn_k(const unsigned short* __restrict__ Qb,
                                              const unsigned short* __restrict__ KVb,
                                              const unsigned short* __restrict__ VT,
                                              unsigned short* __restrict__ Out) {
  int bh = blockIdx.x;
  int b = bh >> 3, h = bh & 7;
  int tid = threadIdx.x;
  int w = tid >> 6, lane = tid & 63, l16 = lane & 15, quad = lane >> 4;
  const unsigned short* Kbase = KVb + (size_t)(b * 512) * 1024 + h * 64;  // row stride 1024
  const unsigned short* Vbase = VT + (size_t)(bh * 64) * 512;             // row stride 512
  f32x4 zf = {0.f, 0.f, 0.f, 0.f};

  int jl[4] = {w, 7 - w, 8 + w, 15 - w};  // w in [0,4): perfect 16-tile partition
  for (int ji = 0; ji < 4; ++ji) {
    int j = jl[ji];
    int q0 = j * 32;
    short8v qF[2][2];
#pragma unroll
    for (int u = 0; u < 2; ++u)
#pragma unroll
      for (int hf = 0; hf < 2; ++hf)
        qF[u][hf] = *(const short8v*)(Qb + (size_t)(b * 512 + q0 + u * 16 + l16) * 512 +
                                      h * 64 + hf * 32 + quad * 8);
    f32x4 O[2][4];
#pragma unroll
    for (int u = 0; u < 2; ++u)
#pragma unroll
      for (int dt = 0; dt < 4; ++dt) O[u][dt] = zf;
    float m_[2] = {-1e30f, -1e30f};
    float l_[2] = {0.f, 0.f};

    for (int kp = 0; kp <= j; ++kp) {
      int kb = kp * 32;
      short8v kF[2][2];
#pragma unroll
      for (int v = 0; v < 2; ++v)
#pragma unroll
        for (int hf = 0; hf < 2; ++hf)
          kF[v][hf] =
              *(const short8v*)(Kbase + (size_t)(kb + v * 16 + l16) * 1024 + hf * 32 + quad * 8);
      // T[kpos][q]: A=K rows, B=Q rows; D: row=kpos(16v+4quad+r), col=q(l16)
      f32x4 S[2][2];
#pragma unroll
      for (int u = 0; u < 2; ++u)
#pragma unroll
        for (int v = 0; v < 2; ++v) {
          f32x4 s0 = __builtin_amdgcn_mfma_f32_16x16x32_bf16(kF[v][0], qF[u][0], zf, 0, 0, 0);
          S[u][v] = __builtin_amdgcn_mfma_f32_16x16x32_bf16(kF[v][1], qF[u][1], s0, 0, 0, 0);
        }
      if (kp == j) {  // only diagonal pair needs causal masking
#pragma unroll
        for (int u = 0; u < 2; ++u)
#pragma unroll
          for (int v = 0; v < 2; ++v)
#pragma unroll
            for (int r = 0; r < 4; ++r)
              if (v * 16 + quad * 4 + r > u * 16 + l16) S[u][v][r] = -1e30f;
      }
      short8v pF[2];
#pragma unroll
      for (int u = 0; u < 2; ++u) {
        float tm = -1e30f;
#pragma unroll
        for (int v = 0; v < 2; ++v)
#pragma unroll
          for (int r = 0; r < 4; ++r) tm = fmaxf(tm, S[u][v][r]);
        tm = fmaxf(tm, __shfl_xor(tm, 16));
        tm = fmaxf(tm, __shfl_xor(tm, 32));
        float nm = fmaxf(m_[u], tm);
        float alpha = __expf(m_[u] - nm);
        float rs = 0.f;
        union { unsigned short u16[8]; short8v v8; } pk;
#pragma unroll
        for (int v = 0; v < 2; ++v)
#pragma unroll
          for (int r = 0; r < 4; ++r) {
            float e = __expf(S[u][v][r] - nm);
            rs += e;
            pk.u16[v * 4 + r] = f2bf(e);  // A-slot jj=4v+r <-> kpos kb+16v+4quad+r
          }
        rs += __shfl_xor(rs, 16);
        rs += __shfl_xor(rs, 32);
        l_[u] = l_[u] * alpha + rs;
        m_[u] = nm;
        float al[4];
#pragma unroll
        for (int r = 0; r < 4; ++r) al[r] = __shfl(alpha, quad * 4 + r);
#pragma unroll
        for (int dt = 0; dt < 4; ++dt)
#pragma unroll
          for (int r = 0; r < 4; ++r) O[u][dt][r] *= al[r];
        pF[u] = pk.v8;
      }
      short8v vF[4];  // B-slot (quad,jj) holds V[kb + 16(jj>>2)+4quad+(jj&3)][d] via sigma
#pragma unroll
      for (int dt = 0; dt < 4; ++dt)
        vF[dt] = *(const short8v*)(Vbase + (size_t)(dt * 16 + l16) * 512 + kb + quad * 8);
#pragma unroll
      for (int u = 0; u < 2; ++u)
#pragma unroll
        for (int dt = 0; dt < 4; ++dt)
          O[u][dt] = __builtin_amdgcn_mfma_f32_16x16x32_bf16(pF[u], vF[dt], O[u][dt], 0, 0, 0);
    }
    // normalize + store: O row(q) = q0+u*16+quad*4+r, col(d) = h*64+dt*16+l16
#pragma unroll
    for (int u = 0; u < 2; ++u) {
      float li = 1.f / l_[u];
      float lr[4];
#pragma unroll
      for (int r = 0; r < 4; ++r) lr[r] = __shfl(li, quad * 4 + r);
#pragma unroll
      for (int dt = 0; dt < 4; ++dt)
#pragma unroll
        for (int r = 0; r < 4; ++r)
          Out[(size_t)(b * 512 + q0 + u * 16 + quad * 4 + r) * 512 + h * 64 + dt * 16 + l16] =
              f2bf(O[u][dt][r] * lr[r]);
    }
  }
}

// -------- head: out[m] = (out0[m,:] + relu(res1[m,:])) . W_out + b_out  (f32 out) --------
__global__ __launch_bounds__(256) void final_k(const unsigned short* __restrict__ out0,
                                               const unsigned short* __restrict__ res1,
                                               const float* __restrict__ wout,
                                               const float* __restrict__ bout,
                                               float* __restrict__ dst) {
  int w = threadIdx.x >> 6, lane = threadIdx.x & 63;
  int row = blockIdx.x * 4 + w;
  const unsigned short* o = out0 + (size_t)row * 512 + lane * 8;
  const unsigned short* r = res1 + (size_t)row * 512 + lane * 8;
  const float* wv = wout + lane * 8;
  float acc = 0.f;
#pragma unroll
  for (int i = 0; i < 8; ++i) {
    float rv = bf2f(r[i]);
    acc += (bf2f(o[i]) + fmaxf(rv, 0.f)) * wv[i];
  }
#pragma unroll
  for (int off = 1; off <= 32; off <<= 1) acc += __shfl_xor(acc, off);
  if (lane == 0) dst[row] = acc + bout[0];
}

extern "C" void kernel_launch(void* const* d_in, const int* in_sizes, int n_in,
                              void* d_out, int out_size, void* d_ws, size_t ws_size,
                              hipStream_t stream) {
  (void)in_sizes; (void)n_in; (void)out_size; (void)ws_size;
  const int* item_inputs = (const int*)d_in[0];
  const int* skill_inputs = (const int*)d_in[1];
  const int* label_inputs = (const int*)d_in[2];
  const int* item_ids = (const int*)d_in[3];
  const int* skill_ids = (const int*)d_in[4];
  const float* item_emb = (const float*)d_in[5];
  const float* skill_emb = (const float*)d_in[6];
  const float* W_in = (const float*)d_in[7];
  const float* b_in = (const float*)d_in[8];
  const float* Wq = (const float*)d_in[9];
  const float* bq = (const float*)d_in[10];
  const float* Wk = (const float*)d_in[11];
  const float* bk = (const float*)d_in[12];
  const float* Wv = (const float*)d_in[13];
  const float* bv = (const float*)d_in[14];
  // d_in[15..21] (Wg,bg,Wtq,btq,Wtk,btk,core): softmax-invariant, unused
  const float* W_out = (const float*)d_in[22];
  const float* b_out = (const float*)d_in[23];

  // workspace layout (bf16 shorts), lifetime-overlapped; high-water ~116 MB
  unsigned short* ws = (unsigned short*)d_ws;
  unsigned short* INP = ws;                            // 16384*1024 (dead after GEMM0)
  unsigned short* OUT0 = ws;                           // overlays INP
  unsigned short* RES1 = ws + (size_t)16384 * 512;     // overlays INP upper half
  unsigned short* QRY = ws + (size_t)16384 * 1024;     // 16384*512
  unsigned short* X = QRY + (size_t)16384 * 512;       // 16384*512 (dead after KV GEMM 0)
  unsigned short* VT = X;                              // 2048*512, overlays X
  unsigned short* Qb = X + (size_t)16384 * 512;        // 16384*512
  unsigned short* KVb = Qb + (size_t)16384 * 512;      // 16384*1024
  unsigned short* WInT = KVb + (size_t)16384 * 1024;   // 1024*512
  unsigned short* WqT0 = WInT + 512 * 1024;            // 512*512
  unsigned short* WqT1 = WqT0 + 512 * 512;
  unsigned short* WkvT0 = WqT1 + 512 * 512;            // 1024*512
  unsigned short* WkvT1 = WkvT0 + 1024 * 512;

  // all 7 weight transposes in one dispatch
  WPtrs p;
  p.s[0] = W_in;           p.d[0] = WInT;
  p.s[1] = Wq;             p.d[1] = WqT0;
  p.s[2] = Wq + 262144;    p.d[2] = WqT1;
  p.s[3] = Wk;             p.d[3] = WkvT0;
  p.s[4] = Wv;             p.d[4] = WkvT0 + 262144;
  p.s[5] = Wk + 262144;    p.d[5] = WkvT1;
  p.s[6] = Wv + 262144;    p.d[6] = WkvT1 + 262144;
  transpose_all_k<<<dim3(16, 128), 256, 0, stream>>>(p);

  build_inputs_k<<<4096, 256, 0, stream>>>(item_inputs, skill_inputs, label_inputs, item_ids,
                                           skill_ids, item_emb, skill_emb, INP, QRY);
  // x = relu(inputs @ W_in + b_in)   (INP dead afterwards)
  gemm_bt_k<<<dim3(128, 4), 256, 0, stream>>>(INP, WInT, X, 1024, 512, b_in, b_in, 1 << 30,
                                              1.0f, 1);

  const float SC = 0.125f;  // 1/sqrt(64), folded into Q projection
  // layer 0 (kv = x)
  gemm_bt_k<<<dim3(128, 4), 256, 0, stream>>>(QRY, WqT0, Qb, 512, 512, bq, bq, 1 << 30, SC, 0);
  gemm_bt_k<<<dim3(128, 8), 256, 0, stream>>>(X, WkvT0, KVb, 512, 1024, bk, bv, 512, 1.0f, 0);
  vperm_k<<<256, 256, 0, stream>>>(KVb, VT);  // X dead -> VT overlays it
  attn_k<<<256, 256, 0, stream>>>(Qb, KVb, VT, OUT0);
  // layer 1 (kv = out0)
  gemm_bt_k<<<dim3(128, 4), 256, 0, stream>>>(QRY, WqT1, Qb, 512, 512, bq + 512, bq + 512,
                                              1 << 30, SC, 0);
  gemm_bt_k<<<dim3(128, 8), 256, 0, stream>>>(OUT0, WkvT1, KVb, 512, 1024, bk + 512, bv + 512,
                                              512, 1.0f, 0);
  vperm_k<<<256, 256, 0, stream>>>(KVb, VT);
  attn_k<<<256, 256, 0, stream>>>(Qb, KVb, VT, RES1);
  // out = (out0 + relu(res1)) @ W_out + b_out   (f32 output)
  final_k<<<4096, 256, 0, stream>>>(OUT0, RES1, W_out, b_out, (float*)d_out);
}

// Round 8
// 357.737 us; speedup vs baseline: 1.7704x; 1.1177x over previous
//
#include <hip/hip_runtime.h>
#include <stdint.h>

// B=32 S=512 E=512 H=8 Dh=64 R=3 L=2 ; M = B*S = 16384
// Inputs: float32 (+int32 indices). Output: float32.
// Internal: bf16 workspace + bf16 MFMA, f32 accumulate.
// glo/ts score terms are per-(b,h,q) constants broadcast over k -> softmax-
// invariant -> Wg/bg/Wtq/btq/Wtk/btk/core are mathematically unused.

typedef short short8v __attribute__((ext_vector_type(8)));
typedef float f32x4 __attribute__((ext_vector_type(4)));

__device__ __forceinline__ float bf2f(unsigned short u) {
  union { unsigned int i; float f; } c;
  c.i = ((unsigned int)u) << 16;
  return c.f;
}
__device__ __forceinline__ unsigned short f2bf(float f) {
  union { float f; unsigned int i; } c;
  c.f = f;
  unsigned int u = c.i + 0x7FFFu + ((c.i >> 16) & 1u);  // RNE
  return (unsigned short)(u >> 16);
}

// async global->LDS, 16B per lane; LDS dest must be wave-uniform base + lane*16
__device__ __forceinline__ void g2l16(const void* g, void* l) {
  __builtin_amdgcn_global_load_lds(
      (const __attribute__((address_space(1))) unsigned int*)g,
      (__attribute__((address_space(3))) unsigned int*)l, 16, 0, 0);
}

// ------------- batched weight transpose (f32 in -> bf16 [N][K] out), 1 dispatch -------------
struct WPtrs {
  const float* s[7];
  unsigned short* d[7];
};
__global__ __launch_bounds__(256) void transpose_all_k(WPtrs p) {
  __shared__ float t[32][33];
  int by = blockIdx.y;
  int mi, r0t;
  if (by < 32) { mi = 0; r0t = by; }            // W_in: 1024 rows
  else { mi = 1 + ((by - 32) >> 4); r0t = (by - 32) & 15; }  // 6x 512-row mats
  const float* in = p.s[mi];
  unsigned short* out = p.d[mi];
  int R = (mi == 0) ? 1024 : 512;  // source rows == out row-stride (K)
  const int C = 512;
  int c0 = blockIdx.x * 32, r0 = r0t * 32;
  int lr = threadIdx.x >> 5, lc = threadIdx.x & 31;
#pragma unroll
  for (int i = 0; i < 4; ++i) {
    int r = lr + i * 8;
    t[r][lc] = in[(size_t)(r0 + r) * C + (c0 + lc)];
  }
  __syncthreads();
#pragma unroll
  for (int i = 0; i < 4; ++i) {
    int r = lr + i * 8;
    out[(size_t)(c0 + r) * R + (r0 + lc)] = f2bf(t[lc][r]);
  }
}

// ------- gather + label-select (f32 emb -> bf16): INP (16384x1024), QRY (16384x512) -------
__global__ __launch_bounds__(256) void build_inputs_k(
    const int* __restrict__ item_in, const int* __restrict__ skill_in,
    const int* __restrict__ label_in, const int* __restrict__ item_id,
    const int* __restrict__ skill_id, const float* __restrict__ iemb,
    const float* __restrict__ semb, unsigned short* __restrict__ INP,
    unsigned short* __restrict__ QRY) {
  int w = threadIdx.x >> 6, lane = threadIdx.x & 63;
  int row = blockIdx.x * 4 + w;
  int ii = item_in[row], si = skill_in[row], lb = label_in[row];
  int iq = item_id[row], sq = skill_id[row];
  int c = lane * 16;
  int k = c & 511;
  const float* src = (k < 256) ? (iemb + (size_t)ii * 256 + k)
                               : (semb + (size_t)si * 256 + (k - 256));
  bool keep = ((lb == 1) == (c < 512));
  union { unsigned short u[16]; int4 v[2]; } o;
#pragma unroll
  for (int i = 0; i < 16; ++i) o.u[i] = keep ? f2bf(src[i]) : 0;
  *(int4*)(INP + (size_t)row * 1024 + c) = o.v[0];
  *(int4*)(INP + (size_t)row * 1024 + c + 8) = o.v[1];
  int qc = lane * 8;
  const float* qs = (qc < 256) ? (iemb + (size_t)iq * 256 + qc)
                               : (semb + (size_t)sq * 256 + (qc - 256));
  union { unsigned short u[8]; int4 v; } q;
#pragma unroll
  for (int i = 0; i < 8; ++i) q.u[i] = f2bf(qs[i]);
  *(int4*)(QRY + (size_t)row * 512 + qc) = q.v;
}

// ------------- GEMM: C[M,N] = epi(A[M,K] @ Bt[N,K]^T) ; MTx128 tile, BK=32 -------------
// MT=128: 2x2 waves of 64x64. MT=64: 1x4 waves of 64x32 (2x blocks for grid-starved shapes).
// global_load_lds width-16 staging; LDS-staged coalesced epilogue.
#define CT_LD 132  // 128 + 4 shorts pad
template <int MT>
__global__ __launch_bounds__(256, 4) void gemm_bt_k(
    const unsigned short* __restrict__ A, const unsigned short* __restrict__ Bt,
    unsigned short* __restrict__ C, int K, int ldc,
    const float* __restrict__ biasA, const float* __restrict__ biasB,
    int nsplit, float scale, int do_relu) {
  constexpr int NT = (MT == 128) ? 4 : 2;  // 16-col tiles per wave
  __shared__ __align__(16) unsigned short uS[MT * CT_LD];
  unsigned short* sA = uS;            // MT x 32
  unsigned short* sB = uS + MT * 32;  // 128 x 32
  unsigned short* Ct = uS;            // MT x 132 in epilogue
  int mb = blockIdx.x, nb = blockIdx.y;
  int tid = threadIdx.x;
  int w = tid >> 6, lane = tid & 63, l16 = lane & 15, quad = lane >> 4;
  int wm = (MT == 128) ? (w & 1) : 0;
  int wn = (MT == 128) ? (w >> 1) : w;
  f32x4 acc[4][NT];
#pragma unroll
  for (int i = 0; i < 4; ++i)
#pragma unroll
    for (int jn = 0; jn < NT; ++jn) acc[i][jn] = (f32x4){0.f, 0.f, 0.f, 0.f};

  for (int k0 = 0; k0 < K; k0 += 32) {
    __syncthreads();  // previous iteration's ds_reads complete before overwrite
#pragma unroll
    for (int j = 0; j < MT / 64; ++j) {  // A tile: MT*4 16B chunks
      int c = j * 256 + tid;
      g2l16(A + (size_t)(mb * MT + (c >> 2)) * K + k0 + (c & 3) * 8, sA + (size_t)c * 8);
    }
#pragma unroll
    for (int j = 0; j < 2; ++j) {  // B tile: 512 chunks
      int c = j * 256 + tid;
      g2l16(Bt + (size_t)(nb * 128 + (c >> 2)) * K + k0 + (c & 3) * 8, sB + (size_t)c * 8);
    }
    __syncthreads();  // barrier drains vmcnt(0) -> LDS ready
    short8v aF[4], bF[NT];
#pragma unroll
    for (int mt = 0; mt < 4; ++mt)
      aF[mt] = *(const short8v*)(sA + (wm * 64 + mt * 16 + l16) * 32 + quad * 8);
#pragma unroll
    for (int nt = 0; nt < NT; ++nt)
      bF[nt] = *(const short8v*)(sB + (wn * (16 * NT) + nt * 16 + l16) * 32 + quad * 8);
#pragma unroll
    for (int mt = 0; mt < 4; ++mt)
#pragma unroll
      for (int nt = 0; nt < NT; ++nt)
        acc[mt][nt] =
            __builtin_amdgcn_mfma_f32_16x16x32_bf16(aF[mt], bF[nt], acc[mt][nt], 0, 0, 0);
  }
  // epilogue: +bias, *scale, optional relu -> bf16 C-tile in LDS -> coalesced store
  __syncthreads();
#pragma unroll
  for (int mt = 0; mt < 4; ++mt)
#pragma unroll
    for (int nt = 0; nt < NT; ++nt) {
      int col = wn * (16 * NT) + nt * 16 + l16;
      int gcol = nb * 128 + col;
      float bs = (gcol < nsplit) ? biasA[gcol] : biasB[gcol - nsplit];
#pragma unroll
      for (int r = 0; r < 4; ++r) {
        int row = wm * 64 + mt * 16 + quad * 4 + r;
        float v = (acc[mt][nt][r] + bs) * scale;
        if (do_relu) v = fmaxf(v, 0.f);
        Ct[row * CT_LD + col] = f2bf(v);
      }
    }
  __syncthreads();
#pragma unroll
  for (int it = 0; it < MT / 16; ++it) {
    int row = it * 16 + (tid >> 4);
    int col8 = (tid & 15) * 8;
    *(int4*)(C + (size_t)(mb * MT + row) * ldc + nb * 128 + col8) =
        *(const int4*)(Ct + row * CT_LD + col8);
  }
}

// ---------------- V transpose + sigma permute (LDS-tiled) ----------------
// VT[(b*8+h)*64 + d][sigma(kp)] = V[b,kp,h*64+d]; sigma within 32-blocks:
// sigma(32T+16t+4q+j) = 32T+8q+4t+j  (inverse: kp = 32T'+16*sg[2]+4*sg[4:3]+sg[1:0]).
// block = (kt, half, b): stages 64 kp x 256 d, writes 256 d-rows x 64 sg-cols.
#define VP_LD 264  // 256 + 8 shorts pad
__global__ __launch_bounds__(256) void vperm_k(const unsigned short* __restrict__ KVb,
                                               unsigned short* __restrict__ VT) {
  __shared__ __align__(16) unsigned short stg[64 * VP_LD];
  int kt = blockIdx.x, half = blockIdx.y, b = blockIdx.z;
  int t = threadIdx.x;
#pragma unroll
  for (int i = 0; i < 8; ++i) {  // 64 rows x 32 int4-chunks
    int ch = i * 256 + t;
    int kp = ch >> 5, c = ch & 31;
    *(int4*)(stg + kp * VP_LD + c * 8) =
        *(const int4*)(KVb + (size_t)(b * 512 + kt * 64 + kp) * 1024 + 512 + half * 256 + c * 8);
  }
  __syncthreads();
#pragma unroll
  for (int i = 0; i < 8; ++i) {  // 256 d-rows x 8 int4-chunks
    int ch = i * 256 + t;
    int d = ch >> 3, cc = ch & 7;
    union { unsigned short u[8]; int4 v; } o;
#pragma unroll
    for (int s = 0; s < 8; ++s) {
      int kp = ((cc >> 2) << 5) | ((s >> 2) << 4) | ((cc & 3) << 2) | (s & 3);
      o.u[s] = stg[kp * VP_LD + d];
    }
    *(int4*)(VT + (size_t)(b * 512 + half * 256 + d) * 512 + kt * 64 + cc * 8) = o.v;
  }
}

// ---------------- fused causal flash attention, LDS-free ----------------
// Qb: [16384][512] bf16, pre-scaled by 1/sqrt(Dh). KVb: [16384][1024] = [K | V].
// VT: [2048][512] sigma-permuted V^T. Out: [16384][512] bf16.
// Scores TRANSPOSED (T = K*Q^T) so softmax'd P is already in MFMA A-layout;
// sigma-permuted V^T makes PV full-rate K=32 MFMAs.
// grid (256 bh, 4 g); wave w takes one q-tile-pair j from {g,7-g,8+g,15-g}
// (34 k-blocks per block; 4 blocks/CU for latency hiding).
__global__ __launch_bounds__(256) void attn_k(const unsigned short* __restrict__ Qb,
                                              const unsigned short* __restrict__ KVb,
                                              const unsigned short* __restrict__ VT,
                                              unsigned short* __restrict__ Out) {
  int bh = blockIdx.x, g = blockIdx.y;
  int b = bh >> 3, h = bh & 7;
  int tid = threadIdx.x;
  int w = tid >> 6, lane = tid & 63, l16 = lane & 15, quad = lane >> 4;
  const unsigned short* Kbase = KVb + (size_t)(b * 512) * 1024 + h * 64;  // row stride 1024
  const unsigned short* Vbase = VT + (size_t)(bh * 64) * 512;             // row stride 512
  f32x4 zf = {0.f, 0.f, 0.f, 0.f};

  int j = (w == 0) ? g : (w == 1) ? (7 - g) : (w == 2) ? (8 + g) : (15 - g);
  int q0 = j * 32;
  short8v qF[2][2];
#pragma unroll
  for (int u = 0; u < 2; ++u)
#pragma unroll
    for (int hf = 0; hf < 2; ++hf)
      qF[u][hf] = *(const short8v*)(Qb + (size_t)(b * 512 + q0 + u * 16 + l16) * 512 +
                                    h * 64 + hf * 32 + quad * 8);
  f32x4 O[2][4];
#pragma unroll
  for (int u = 0; u < 2; ++u)
#pragma unroll
    for (int dt = 0; dt < 4; ++dt) O[u][dt] = zf;
  float m_[2] = {-1e30f, -1e30f};
  float l_[2] = {0.f, 0.f};

  for (int kp = 0; kp <= j; ++kp) {
    int kb = kp * 32;
    short8v kF[2][2];
#pragma unroll
    for (int v = 0; v < 2; ++v)
#pragma unroll
      for (int hf = 0; hf < 2; ++hf)
        kF[v][hf] =
            *(const short8v*)(Kbase + (size_t)(kb + v * 16 + l16) * 1024 + hf * 32 + quad * 8);
    // T[kpos][q]: A=K rows, B=Q rows; D: row=kpos(16v+4quad+r), col=q(l16)
    f32x4 S[2][2];
#pragma unroll
    for (int u = 0; u < 2; ++u)
#pragma unroll
      for (int v = 0; v < 2; ++v) {
        f32x4 s0 = __builtin_amdgcn_mfma_f32_16x16x32_bf16(kF[v][0], qF[u][0], zf, 0, 0, 0);
        S[u][v] = __builtin_amdgcn_mfma_f32_16x16x32_bf16(kF[v][1], qF[u][1], s0, 0, 0, 0);
      }
    if (kp == j) {  // only diagonal pair needs causal masking
#pragma unroll
      for (int u = 0; u < 2; ++u)
#pragma unroll
        for (int v = 0; v < 2; ++v)
#pragma unroll
          for (int r = 0; r < 4; ++r)
            if (v * 16 + quad * 4 + r > u * 16 + l16) S[u][v][r] = -1e30f;
    }
    short8v pF[2];
#pragma unroll
    for (int u = 0; u < 2; ++u) {
      float tm = -1e30f;
#pragma unroll
      for (int v = 0; v < 2; ++v)
#pragma unroll
        for (int r = 0; r < 4; ++r) tm = fmaxf(tm, S[u][v][r]);
      tm = fmaxf(tm, __shfl_xor(tm, 16));
      tm = fmaxf(tm, __shfl_xor(tm, 32));
      float nm = fmaxf(m_[u], tm);
      float alpha = __expf(m_[u] - nm);
      float rs = 0.f;
      union { unsigned short u16[8]; short8v v8; } pk;
#pragma unroll
      for (int v = 0; v < 2; ++v)
#pragma unroll
        for (int r = 0; r < 4; ++r) {
          float e = __expf(S[u][v][r] - nm);
          rs += e;
          pk.u16[v * 4 + r] = f2bf(e);  // A-slot jj=4v+r <-> kpos kb+16v+4quad+r
        }
      rs += __shfl_xor(rs, 16);
      rs += __shfl_xor(rs, 32);
      l_[u] = l_[u] * alpha + rs;
      m_[u] = nm;
      float al[4];
#pragma unroll
      for (int r = 0; r < 4; ++r) al[r] = __shfl(alpha, quad * 4 + r);
#pragma unroll
      for (int dt = 0; dt < 4; ++dt)
#pragma unroll
        for (int r = 0; r < 4; ++r) O[u][dt][r] *= al[r];
      pF[u] = pk.v8;
    }
    short8v vF[4];  // B-slot (quad,jj) holds V[kb + 16(jj>>2)+4quad+(jj&3)][d] via sigma
#pragma unroll
    for (int dt = 0; dt < 4; ++dt)
      vF[dt] = *(const short8v*)(Vbase + (size_t)(dt * 16 + l16) * 512 + kb + quad * 8);
#pragma unroll
    for (int u = 0; u < 2; ++u)
#pragma unroll
      for (int dt = 0; dt < 4; ++dt)
        O[u][dt] = __builtin_amdgcn_mfma_f32_16x16x32_bf16(pF[u], vF[dt], O[u][dt], 0, 0, 0);
  }
  // normalize + store: O row(q) = q0+u*16+quad*4+r, col(d) = h*64+dt*16+l16
#pragma unroll
  for (int u = 0; u < 2; ++u) {
    float li = 1.f / l_[u];
    float lr[4];
#pragma unroll
    for (int r = 0; r < 4; ++r) lr[r] = __shfl(li, quad * 4 + r);
#pragma unroll
    for (int dt = 0; dt < 4; ++dt)
#pragma unroll
      for (int r = 0; r < 4; ++r)
        Out[(size_t)(b * 512 + q0 + u * 16 + quad * 4 + r) * 512 + h * 64 + dt * 16 + l16] =
            f2bf(O[u][dt][r] * lr[r]);
  }
}

// -------- head: out[m] = (out0[m,:] + relu(res1[m,:])) . W_out + b_out  (f32 out) --------
__global__ __launch_bounds__(256) void final_k(const unsigned short* __restrict__ out0,
                                               const unsigned short* __restrict__ res1,
                                               const float* __restrict__ wout,
                                               const float* __restrict__ bout,
                                               float* __restrict__ dst) {
  int w = threadIdx.x >> 6, lane = threadIdx.x & 63;
  int row = blockIdx.x * 4 + w;
  const unsigned short* o = out0 + (size_t)row * 512 + lane * 8;
  const unsigned short* r = res1 + (size_t)row * 512 + lane * 8;
  const float* wv = wout + lane * 8;
  float acc = 0.f;
#pragma unroll
  for (int i = 0; i < 8; ++i) {
    float rv = bf2f(r[i]);
    acc += (bf2f(o[i]) + fmaxf(rv, 0.f)) * wv[i];
  }
#pragma unroll
  for (int off = 1; off <= 32; off <<= 1) acc += __shfl_xor(acc, off);
  if (lane == 0) dst[row] = acc + bout[0];
}

extern "C" void kernel_launch(void* const* d_in, const int* in_sizes, int n_in,
                              void* d_out, int out_size, void* d_ws, size_t ws_size,
                              hipStream_t stream) {
  (void)in_sizes; (void)n_in; (void)out_size; (void)ws_size;
  const int* item_inputs = (const int*)d_in[0];
  const int* skill_inputs = (const int*)d_in[1];
  const int* label_inputs = (const int*)d_in[2];
  const int* item_ids = (const int*)d_in[3];
  const int* skill_ids = (const int*)d_in[4];
  const float* item_emb = (const float*)d_in[5];
  const float* skill_emb = (const float*)d_in[6];
  const float* W_in = (const float*)d_in[7];
  const float* b_in = (const float*)d_in[8];
  const float* Wq = (const float*)d_in[9];
  const float* bq = (const float*)d_in[10];
  const float* Wk = (const float*)d_in[11];
  const float* bk = (const float*)d_in[12];
  const float* Wv = (const float*)d_in[13];
  const float* bv = (const float*)d_in[14];
  // d_in[15..21] (Wg,bg,Wtq,btq,Wtk,btk,core): softmax-invariant, unused
  const float* W_out = (const float*)d_in[22];
  const float* b_out = (const float*)d_in[23];

  // workspace layout (bf16 shorts), lifetime-overlapped; high-water ~116 MB
  unsigned short* ws = (unsigned short*)d_ws;
  unsigned short* INP = ws;                            // 16384*1024 (dead after GEMM0)
  unsigned short* OUT0 = ws;                           // overlays INP
  unsigned short* RES1 = ws + (size_t)16384 * 512;     // overlays INP upper half
  unsigned short* QRY = ws + (size_t)16384 * 1024;     // 16384*512
  unsigned short* X = QRY + (size_t)16384 * 512;       // 16384*512 (dead after KV GEMM 0)
  unsigned short* VT = X;                              // 2048*512, overlays X
  unsigned short* Qb = X + (size_t)16384 * 512;        // 16384*512
  unsigned short* KVb = Qb + (size_t)16384 * 512;      // 16384*1024
  unsigned short* WInT = KVb + (size_t)16384 * 1024;   // 1024*512
  unsigned short* WqT0 = WInT + 512 * 1024;            // 512*512
  unsigned short* WqT1 = WqT0 + 512 * 512;
  unsigned short* WkvT0 = WqT1 + 512 * 512;            // 1024*512
  unsigned short* WkvT1 = WkvT0 + 1024 * 512;

  WPtrs p;
  p.s[0] = W_in;           p.d[0] = WInT;
  p.s[1] = Wq;             p.d[1] = WqT0;
  p.s[2] = Wq + 262144;    p.d[2] = WqT1;
  p.s[3] = Wk;             p.d[3] = WkvT0;
  p.s[4] = Wv;             p.d[4] = WkvT0 + 262144;
  p.s[5] = Wk + 262144;    p.d[5] = WkvT1;
  p.s[6] = Wv + 262144;    p.d[6] = WkvT1 + 262144;
  transpose_all_k<<<dim3(16, 128), 256, 0, stream>>>(p);

  build_inputs_k<<<4096, 256, 0, stream>>>(item_inputs, skill_inputs, label_inputs, item_ids,
                                           skill_ids, item_emb, skill_emb, INP, QRY);
  // x = relu(inputs @ W_in + b_in)   (INP dead afterwards)
  gemm_bt_k<64><<<dim3(256, 4), 256, 0, stream>>>(INP, WInT, X, 1024, 512, b_in, b_in,
                                                  1 << 30, 1.0f, 1);

  const float SC = 0.125f;  // 1/sqrt(64), folded into Q projection
  // layer 0 (kv = x)
  gemm_bt_k<64><<<dim3(256, 4), 256, 0, stream>>>(QRY, WqT0, Qb, 512, 512, bq, bq, 1 << 30,
                                                  SC, 0);
  gemm_bt_k<128><<<dim3(128, 8), 256, 0, stream>>>(X, WkvT0, KVb, 512, 1024, bk, bv, 512,
                                                   1.0f, 0);
  vperm_k<<<dim3(8, 2, 32), 256, 0, stream>>>(KVb, VT);  // X dead -> VT overlays it
  attn_k<<<dim3(256, 4), 256, 0, stream>>>(Qb, KVb, VT, OUT0);
  // layer 1 (kv = out0)
  gemm_bt_k<64><<<dim3(256, 4), 256, 0, stream>>>(QRY, WqT1, Qb, 512, 512, bq + 512,
                                                  bq + 512, 1 << 30, SC, 0);
  gemm_bt_k<128><<<dim3(128, 8), 256, 0, stream>>>(OUT0, WkvT1, KVb, 512, 1024, bk + 512,
                                                   bv + 512, 512, 1.0f, 0);
  vperm_k<<<dim3(8, 2, 32), 256, 0, stream>>>(KVb, VT);
  attn_k<<<dim3(256, 4), 256, 0, stream>>>(Qb, KVb, VT, RES1);
  // out = (out0 + relu(res1)) @ W_out + b_out   (f32 output)
  final_k<<<4096, 256, 0, stream>>>(OUT0, RES1, W_out, b_out, (float*)d_out);
}